// Round 1
// 653.856 us; speedup vs baseline: 1.0184x; 1.0184x over previous
//
#include <hip/hip_runtime.h>
#include <hip/hip_bf16.h>

#define NN 100000
#define EE 500000
#define BB 4096
#define HC 128
#define SCAN_ELEM 1024
#define NSB ((NN + SCAN_ELEM - 1) / SCAN_ELEM)   // 98 blocks

typedef __bf16 bf16_t;
typedef bf16_t bf16x8 __attribute__((ext_vector_type(8)));
typedef float f32x4 __attribute__((ext_vector_type(4)));

__device__ __forceinline__ unsigned short f2bf(float f) {
    unsigned u = __builtin_bit_cast(unsigned, f);
    u += 0x7FFFu + ((u >> 16) & 1u);            // RNE
    return (unsigned short)(u >> 16);
}
__device__ __forceinline__ float bflo(unsigned u) {   // low bf16 -> f32
    return __builtin_bit_cast(float, u << 16);
}
__device__ __forceinline__ float bfhi(unsigned u) {   // high bf16 -> f32
    return __builtin_bit_cast(float, u & 0xFFFF0000u);
}

// ---- convert fp32 -> bf16, 4 elems/thread ----------------------------------
__global__ __launch_bounds__(256) void conv_x(const float* __restrict__ in,
                                              unsigned short* __restrict__ outb,
                                              int total4)
{
    const int g = blockIdx.x * 256 + threadIdx.x;
    if (g >= total4) return;
    const float4 f = *(const float4*)(in + (size_t)g * 4);
    ushort4 u;
    u.x = f2bf(f.x); u.y = f2bf(f.y); u.z = f2bf(f.z); u.w = f2bf(f.w);
    *(ushort4*)(outb + (size_t)g * 4) = u;
}

// ---- convert + transpose weights: W[k,n] fp32 -> Wt[p][n*K+k] bf16 ---------
__global__ __launch_bounds__(256) void prep_w(
    const float* __restrict__ Wq, const float* __restrict__ Wk,
    const float* __restrict__ Wv, const float* __restrict__ Ws,
    unsigned short* __restrict__ Wt, int K)
{
    const int g = blockIdx.x * 256 + threadIdx.x;
    const int per = K * 128;
    if (g >= 4 * per) return;
    const int p = g / per, r = g - p * per;
    const int k = r >> 7, n = r & 127;
    const float* W = p == 0 ? Wq : p == 1 ? Wk : p == 2 ? Wv : Ws;
    Wt[(size_t)p * per + (size_t)n * K + k] = f2bf(W[k * 128 + n]);
}

// ---- MFMA GEMM: block = 4 waves = 4 planes, 32-row tile, 128 cols ----------
// Q,K,V stored packed bf16 (pair per dword); S (skip) stored fp32.
template<int NKT>
__global__ __launch_bounds__(256) void gemm_mfma(
    const unsigned short* __restrict__ A,
    const unsigned short* __restrict__ Wt,
    const float* __restrict__ bq, const float* __restrict__ bk,
    const float* __restrict__ bv, const float* __restrict__ bs,
    unsigned* __restrict__ Qb, unsigned* __restrict__ Kb,
    unsigned* __restrict__ Vb, float* __restrict__ S)
{
    constexpr int K = NKT * 32;
    const int lane = threadIdx.x & 63;
    const int p = threadIdx.x >> 6;              // wave == plane
    const int m = lane & 15, kq = lane >> 4;
    const int rows0 = blockIdx.x * 32;

    const unsigned short* Wp = Wt + (size_t)p * 128 * K;
    const float* bias = p == 0 ? bq : p == 1 ? bk : p == 2 ? bv : bs;

    bf16x8 a[2][NKT];
#pragma unroll
    for (int mt = 0; mt < 2; mt++)
#pragma unroll
        for (int kt = 0; kt < NKT; kt++)
            a[mt][kt] = *(const bf16x8*)(A + (size_t)(rows0 + mt * 16 + m) * K + kt * 32 + kq * 8);

    f32x4 acc[2][8];
#pragma unroll
    for (int mt = 0; mt < 2; mt++)
#pragma unroll
        for (int nt = 0; nt < 8; nt++)
            acc[mt][nt] = (f32x4){0.f, 0.f, 0.f, 0.f};

#pragma unroll
    for (int nt = 0; nt < 8; nt++) {
#pragma unroll
        for (int kt = 0; kt < NKT; kt++) {
            const bf16x8 b = *(const bf16x8*)(Wp + (size_t)(nt * 16 + m) * K + kt * 32 + kq * 8);
            acc[0][nt] = __builtin_amdgcn_mfma_f32_16x16x32_bf16(a[0][kt], b, acc[0][nt], 0, 0, 0);
            acc[1][nt] = __builtin_amdgcn_mfma_f32_16x16x32_bf16(a[1][kt], b, acc[1][nt], 0, 0, 0);
        }
    }

    if (p == 3) {
#pragma unroll
        for (int nt = 0; nt < 8; nt++) {
            const float bi = bias[nt * 16 + m];
#pragma unroll
            for (int mt = 0; mt < 2; mt++) {
                float* o = S + (size_t)(rows0 + mt * 16 + kq * 4) * HC + nt * 16 + m;
#pragma unroll
                for (int r = 0; r < 4; r++) o[r * HC] = acc[mt][nt][r] + bi;
            }
        }
    } else {
        unsigned* out = p == 0 ? Qb : p == 1 ? Kb : Vb;
#pragma unroll
        for (int nt = 0; nt < 8; nt++) {
            const float bi = bias[nt * 16 + m];
#pragma unroll
            for (int mt = 0; mt < 2; mt++) {
#pragma unroll
                for (int r = 0; r < 4; r++) {
                    const float v0 = acc[mt][nt][r] + bi;
                    const float v1 = __shfl_xor(v0, 1);
                    if (!(m & 1)) {
                        const unsigned pk = (unsigned)f2bf(v0) | ((unsigned)f2bf(v1) << 16);
                        out[(size_t)(rows0 + mt * 16 + kq * 4 + r) * 64 + nt * 8 + (m >> 1)] = pk;
                    }
                }
            }
        }
    }
}

// ---- CSR build: degree histogram -> hierarchical scan -> bucket scatter -----
__global__ __launch_bounds__(256) void deg_k(const int* __restrict__ ei, int* __restrict__ deg)
{
    const int e = blockIdx.x * 256 + threadIdx.x;
    if (e < EE) atomicAdd(&deg[ei[EE + e]], 1);
}

__global__ __launch_bounds__(256) void scan_part(const int* __restrict__ deg,
                                                 int* __restrict__ bsum)
{
    __shared__ int red[256];
    const int base = blockIdx.x * SCAN_ELEM + threadIdx.x * 4;
    int s = 0;
#pragma unroll
    for (int j = 0; j < 4; j++) { const int i = base + j; if (i < NN) s += deg[i]; }
    red[threadIdx.x] = s;
    __syncthreads();
    for (int st = 128; st > 0; st >>= 1) {
        if (threadIdx.x < st) red[threadIdx.x] += red[threadIdx.x + st];
        __syncthreads();
    }
    if (threadIdx.x == 0) bsum[blockIdx.x] = red[0];
}

__global__ __launch_bounds__(128) void scan_top(const int* __restrict__ bsum,
                                                int* __restrict__ boff)
{
    __shared__ int buf[128];
    const int v = (threadIdx.x < NSB) ? bsum[threadIdx.x] : 0;
    buf[threadIdx.x] = v;
    __syncthreads();
    for (int s = 1; s < 128; s <<= 1) {
        const int t = (threadIdx.x >= s) ? buf[threadIdx.x - s] : 0;
        __syncthreads();
        buf[threadIdx.x] += t;
        __syncthreads();
    }
    if (threadIdx.x < NSB) boff[threadIdx.x] = buf[threadIdx.x] - v;
}

__global__ __launch_bounds__(256) void scan_final(const int* __restrict__ deg,
                                                  const int* __restrict__ boff,
                                                  int* __restrict__ off,
                                                  int* __restrict__ cursor)
{
    __shared__ int tsum[256];
    const int base = blockIdx.x * SCAN_ELEM + threadIdx.x * 4;
    int vals[4];
    int s = 0;
#pragma unroll
    for (int j = 0; j < 4; j++) {
        const int i = base + j;
        vals[j] = (i < NN) ? deg[i] : 0;
        s += vals[j];
    }
    tsum[threadIdx.x] = s;
    __syncthreads();
    for (int st = 1; st < 256; st <<= 1) {
        const int t = (threadIdx.x >= st) ? tsum[threadIdx.x - st] : 0;
        __syncthreads();
        tsum[threadIdx.x] += t;
        __syncthreads();
    }
    int ex = boff[blockIdx.x] + tsum[threadIdx.x] - s;
#pragma unroll
    for (int j = 0; j < 4; j++) {
        const int i = base + j;
        if (i < NN) { off[i] = ex; cursor[i] = ex; }
        ex += vals[j];
    }
    if (blockIdx.x == NSB - 1 && threadIdx.x == 255)
        off[NN] = boff[blockIdx.x] + tsum[255];
}

// bucket: write src node id AND reordered edge_attr at CSR slot (kills the
// eids->ei indirection and the random ea reads in the hot edge kernel).
__global__ __launch_bounds__(256) void bucket_k(const int* __restrict__ ei,
                                                const float* __restrict__ ea,
                                                int* __restrict__ cursor,
                                                int* __restrict__ esrc,
                                                float4* __restrict__ eaf)
{
    const int e = blockIdx.x * 256 + threadIdx.x;
    if (e < EE) {
        const int d = ei[EE + e];
        const int p = atomicAdd(&cursor[d], 1);
        esrc[p] = ei[e];
        eaf[p] = *(const float4*)(ea + (size_t)e * 4);
    }
}

__global__ __launch_bounds__(256) void cnt_k(const int* __restrict__ batch,
                                             float* __restrict__ cnt)
{
    const int n = blockIdx.x * 256 + threadIdx.x;
    if (n < NN) atomicAdd(&cnt[batch[n]], 1.0f);
}

// ---- Fused edge stage: one wave per dst node, 4 edges in flight. -----------
// Lane decomposition: lane = slot*16 + c8.  slot in [0,4) = concurrent edge
// slot; c8 in [0,16) owns 8 channels (= one dwordx4 of packed bf16, matching
// the GEMM's Q/K/V layout directly).  Per-head softmax reduce is xor 1,2
// (DPP quad_perm, cheap) per 4 edges instead of xor 1,2,4,8 per edge; the
// cross-slot combine (xor 16,32) runs once per node.
// fuse_pool=0: out = relu(msg/den + skip) -> bf16 Hb (next GEMM input).
// fuse_pool=1: out = msg/den + skip -> atomicAdd into pooled[batch[n]].
__global__ __launch_bounds__(256) void edge_fused(
    const int* __restrict__ esrc, const float4* __restrict__ eaf,
    const float* __restrict__ We,
    const unsigned* __restrict__ Qb, const unsigned* __restrict__ Kb,
    const unsigned* __restrict__ Vb,
    const int* __restrict__ off, const float* __restrict__ S,
    unsigned short* __restrict__ Hb,
    const int* __restrict__ batch, float* __restrict__ pooled,
    int fuse_pool)
{
    const int lane = threadIdx.x & 63;
    const int slot = lane >> 4;          // edge slot 0..3
    const int c8   = lane & 15;          // channel group: channels c8*8 .. c8*8+7
    const int n = blockIdx.x * 4 + (threadIdx.x >> 6);

    // We slice for my 8 channels: w[d][j], contiguous float4 pairs
    float w[4][8];
#pragma unroll
    for (int d = 0; d < 4; d++) {
        const float4 a = *(const float4*)(We + d * HC + c8 * 8);
        const float4 b = *(const float4*)(We + d * HC + c8 * 8 + 4);
        w[d][0] = a.x; w[d][1] = a.y; w[d][2] = a.z; w[d][3] = a.w;
        w[d][4] = b.x; w[d][5] = b.y; w[d][6] = b.z; w[d][7] = b.w;
    }

    // q for my 8 channels (same row for all 4 slots -> L1 broadcast)
    const uint4 qv = *(const uint4*)(Qb + (size_t)n * 64 + c8 * 4);
    float q[8];
    q[0] = bflo(qv.x); q[1] = bfhi(qv.x); q[2] = bflo(qv.y); q[3] = bfhi(qv.y);
    q[4] = bflo(qv.z); q[5] = bfhi(qv.z); q[6] = bflo(qv.w); q[7] = bfhi(qv.w);

    const int beg = off[n], end = off[n + 1];
    float num[8] = {0.f, 0.f, 0.f, 0.f, 0.f, 0.f, 0.f, 0.f};
    float den = 0.f;

    if (beg < end) {
        int p0 = beg + slot; if (p0 >= end) p0 = end - 1;
        int src = esrc[p0];
        float4 a4 = eaf[p0];
        for (int base = beg; base < end; base += 4) {
            const bool act = (base + slot) < end;
            const uint4 ku = *(const uint4*)(Kb + (size_t)src * 64 + c8 * 4);
            const uint4 vu = *(const uint4*)(Vb + (size_t)src * 64 + c8 * 4);
            const float4 ac = a4;
            if (base + 4 < end) {                 // prefetch next quad
                int pn = base + 4 + slot; if (pn >= end) pn = end - 1;
                src = esrc[pn];
                a4 = eaf[pn];
            }
            float e[8];
#pragma unroll
            for (int j = 0; j < 8; j++)
                e[j] = ac.x * w[0][j] + ac.y * w[1][j] + ac.z * w[2][j] + ac.w * w[3][j];
            float part = q[0] * (bflo(ku.x) + e[0]) + q[1] * (bfhi(ku.x) + e[1])
                       + q[2] * (bflo(ku.y) + e[2]) + q[3] * (bfhi(ku.y) + e[3])
                       + q[4] * (bflo(ku.z) + e[4]) + q[5] * (bfhi(ku.z) + e[5])
                       + q[6] * (bflo(ku.w) + e[6]) + q[7] * (bfhi(ku.w) + e[7]);
            part += __shfl_xor(part, 1);          // DPP quad_perm
            part += __shfl_xor(part, 2);          // -> head sum (32 ch / 4 lanes)
            float al = __expf(part * 0.17677669529663687f);  // 1/sqrt(32)
            if (!act) al = 0.f;
            num[0] += (bflo(vu.x) + e[0]) * al;
            num[1] += (bfhi(vu.x) + e[1]) * al;
            num[2] += (bflo(vu.y) + e[2]) * al;
            num[3] += (bfhi(vu.y) + e[3]) * al;
            num[4] += (bflo(vu.z) + e[4]) * al;
            num[5] += (bfhi(vu.z) + e[5]) * al;
            num[6] += (bflo(vu.w) + e[6]) * al;
            num[7] += (bfhi(vu.w) + e[7]) * al;
            den += al;
        }
    }

    // combine the 4 edge slots (once per node)
#pragma unroll
    for (int j = 0; j < 8; j++) {
        num[j] += __shfl_xor(num[j], 16);
        num[j] += __shfl_xor(num[j], 32);
    }
    den += __shfl_xor(den, 16);
    den += __shfl_xor(den, 32);
    const float inv = 1.f / (den + 1e-16f);

    if (!fuse_pool) {
        if (slot == 0) {                 // 16 lanes write the full 256 B row
            const float4 s0 = *(const float4*)(S + (size_t)n * HC + c8 * 8);
            const float4 s1 = *(const float4*)(S + (size_t)n * HC + c8 * 8 + 4);
            float o[8];
            o[0] = fmaxf(num[0] * inv + s0.x, 0.f);
            o[1] = fmaxf(num[1] * inv + s0.y, 0.f);
            o[2] = fmaxf(num[2] * inv + s0.z, 0.f);
            o[3] = fmaxf(num[3] * inv + s0.w, 0.f);
            o[4] = fmaxf(num[4] * inv + s1.x, 0.f);
            o[5] = fmaxf(num[5] * inv + s1.y, 0.f);
            o[6] = fmaxf(num[6] * inv + s1.z, 0.f);
            o[7] = fmaxf(num[7] * inv + s1.w, 0.f);
            uint4 pk;
            pk.x = (unsigned)f2bf(o[0]) | ((unsigned)f2bf(o[1]) << 16);
            pk.y = (unsigned)f2bf(o[2]) | ((unsigned)f2bf(o[3]) << 16);
            pk.z = (unsigned)f2bf(o[4]) | ((unsigned)f2bf(o[5]) << 16);
            pk.w = (unsigned)f2bf(o[6]) | ((unsigned)f2bf(o[7]) << 16);
            *(uint4*)(Hb + (size_t)n * HC + c8 * 8) = pk;
        }
    } else {
        // every lane adds 2 channels: slot s covers offsets {2s, 2s+1} of the
        // c8 group (static register indices via branch -> cndmask, no scratch)
        float oe, oo;
        if      (slot == 0) { oe = num[0]; oo = num[1]; }
        else if (slot == 1) { oe = num[2]; oo = num[3]; }
        else if (slot == 2) { oe = num[4]; oo = num[5]; }
        else                { oe = num[6]; oo = num[7]; }
        const int c = c8 * 8 + slot * 2;
        const float2 s2 = *(const float2*)(S + (size_t)n * HC + c);
        const int b = batch[n];
        atomicAdd(pooled + (size_t)b * HC + c,     oe * inv + s2.x);
        atomicAdd(pooled + (size_t)b * HC + c + 1, oo * inv + s2.y);
    }
}

__global__ __launch_bounds__(256) void head_k(
    const float* __restrict__ pooled, const float* __restrict__ cnt,
    const int* __restrict__ rt, const float* __restrict__ hW,
    const float* __restrict__ hb, float* __restrict__ out)
{
    const int lane = threadIdx.x & 63;
    const int b = blockIdx.x * 4 + (threadIdx.x >> 6);
    if (b >= BB) return;
    const int t = rt[b];
    const int c = lane * 2;
    const float2 p2 = *(const float2*)(pooled + (size_t)b * HC + c);
    const float2 w2 = *(const float2*)(hW + (size_t)t * HC + c);
    float part = p2.x * w2.x + p2.y * w2.y;
    part += __shfl_xor(part, 1);
    part += __shfl_xor(part, 2);
    part += __shfl_xor(part, 4);
    part += __shfl_xor(part, 8);
    part += __shfl_xor(part, 16);
    part += __shfl_xor(part, 32);
    if (lane == 0) out[b] = part / fmaxf(cnt[b], 1.0f) + hb[t];
}

extern "C" void kernel_launch(void* const* d_in, const int* in_sizes, int n_in,
                              void* d_out, int out_size, void* d_ws, size_t ws_size,
                              hipStream_t stream) {
    const float* x      = (const float*)d_in[0];
    const int*   ei     = (const int*)d_in[1];
    const float* ea     = (const float*)d_in[2];
    const int*   batch  = (const int*)d_in[3];
    const int*   rt     = (const int*)d_in[4];

    // workspace layout — big 16B-aligned arrays first; ~166 MB total
    float* ws     = (float*)d_ws;
    float* Hbuf   = ws;                                   // 12,800,000 f (S plane)
    unsigned* Qb  = (unsigned*)(ws + 12800000);           // 6,400,000 u32 (packed bf16)
    unsigned* Kb  = Qb + 6400000;                         // 6,400,000
    unsigned* Vb  = Kb + 6400000;                         // 6,400,000
    unsigned short* Abf = (unsigned short*)(Vb + 6400000);// 12,800,000 us
    float4* eaf   = (float4*)(Abf + 12800000);            // 500,000 float4
    unsigned short* Wt = (unsigned short*)(eaf + 500000); // 65,536 us
    float* pooled = (float*)(Wt + 65536);                 // 524,288 f
    float* cnt    = pooled + 524288;                      // 4,096 f
    int*   esrc   = (int*)(cnt + 4096);                   // 500,000 i
    int*   deg    = esrc + 500000;                        // 100,000 i
    int*   off    = deg + 100000;                         // 100,001 i (+pad)
    int*   cursor = off + 100004;                         // 100,000 i
    int*   bsum   = cursor + 100000;                      // 128 i
    int*   boff   = bsum + 128;                           // 128 i

    // ---- CSR build (graph identical every call; ws re-poisoned each call)
    hipMemsetAsync(deg, 0, 100000 * sizeof(int), stream);
    deg_k<<<(EE + 255) / 256, 256, 0, stream>>>(ei, deg);
    scan_part<<<NSB, 256, 0, stream>>>(deg, bsum);
    scan_top<<<1, 128, 0, stream>>>(bsum, boff);
    scan_final<<<NSB, 256, 0, stream>>>(deg, boff, off, cursor);
    bucket_k<<<(EE + 255) / 256, 256, 0, stream>>>(ei, ea, cursor, esrc, eaf);

    // pooled/cnt zero + counts (pooled is written only by layer-3 edge_fused)
    hipMemsetAsync(pooled, 0, (size_t)(BB * HC + BB) * sizeof(float), stream);
    cnt_k<<<(NN + 255) / 256, 256, 0, stream>>>(batch, cnt);

    // layer-1 input -> bf16
    conv_x<<<(NN * 64 / 4 + 255) / 256, 256, 0, stream>>>(x, Abf, NN * 64 / 4);

    for (int l = 0; l < 3; l++) {
        const int K = (l == 0) ? 64 : 128;
        const float *Wq, *Wk, *Wv, *Wsk, *bq, *bk, *bv, *bs, *We;
        if (l == 0) {
            Wq = (const float*)d_in[5];  bq = (const float*)d_in[6];
            Wk = (const float*)d_in[7];  bk = (const float*)d_in[8];
            Wv = (const float*)d_in[9];  bv = (const float*)d_in[10];
            We = (const float*)d_in[11];
            Wsk= (const float*)d_in[12]; bs = (const float*)d_in[13];
        } else {
            const int j = l - 1;
            Wq = (const float*)d_in[14] + (size_t)j * HC * HC;  bq = (const float*)d_in[15] + j * HC;
            Wk = (const float*)d_in[16] + (size_t)j * HC * HC;  bk = (const float*)d_in[17] + j * HC;
            Wv = (const float*)d_in[18] + (size_t)j * HC * HC;  bv = (const float*)d_in[19] + j * HC;
            We = (const float*)d_in[20] + (size_t)j * 4 * HC;
            Wsk= (const float*)d_in[21] + (size_t)j * HC * HC;  bs = (const float*)d_in[22] + j * HC;
        }

        prep_w<<<(4 * K * 128 + 255) / 256, 256, 0, stream>>>(Wq, Wk, Wv, Wsk, Wt, K);
        if (K == 64)
            gemm_mfma<2><<<NN / 32, 256, 0, stream>>>(Abf, Wt, bq, bk, bv, bs, Qb, Kb, Vb, Hbuf);
        else
            gemm_mfma<4><<<NN / 32, 256, 0, stream>>>(Abf, Wt, bq, bk, bv, bs, Qb, Kb, Vb, Hbuf);
        edge_fused<<<NN / 4, 256, 0, stream>>>(esrc, eaf, We, Qb, Kb, Vb, off,
                                               Hbuf, Abf, batch, pooled,
                                               l == 2 ? 1 : 0);
    }

    head_k<<<BB / 4, 256, 0, stream>>>(pooled, cnt, rt,
        (const float*)d_in[23], (const float*)d_in[24], (float*)d_out);
}